// Round 4
// baseline (297.725 us; speedup 1.0000x reference)
//
#include <hip/hip_runtime.h>
#include <stdint.h>

#define B_ 2048
#define T_ 256
#define V_ 128
#define E_ 128
#define H_ 64
#define G4_ 256  // 4*H
#define POS_W 20.0f

typedef _Float16 half1;
typedef _Float16 half2_t __attribute__((ext_vector_type(2)));

#if __has_builtin(__builtin_amdgcn_exp2f)
#define EXP2F(x) __builtin_amdgcn_exp2f(x)
#else
#define EXP2F(x) exp2f(x)
#endif

#if __has_builtin(__builtin_amdgcn_rcpf)
#define RCPF(x) __builtin_amdgcn_rcpf(x)
#else
#define RCPF(x) (1.0f / (x))
#endif

__device__ __forceinline__ half2_t bchalf2(uint32_t u) {
    return __builtin_bit_cast(half2_t, u);
}

// asm dot2 with "v" constraints (operands must be arch VGPRs at use).
__device__ __forceinline__ float fdot2(half2_t a, half2_t b, float c) {
    float d;
    asm("v_dot2_f32_f16 %0, %1, %2, %3" : "=v"(d) : "v"(a), "v"(b), "v"(c));
    return d;
}

__device__ __forceinline__ float sigm(float x) {
    // 1/(1+2^(-x*log2e)); saturates correctly at +-inf (rcp(inf)=0)
    return RCPF(1.0f + EXP2F(-1.44269504f * x));
}

__device__ __forceinline__ float tanhr(float x) {
    // tanh(x) = 1 - 2/(e^(2x)+1); exp2 under/overflow saturates to -1/+1
    float t = EXP2F(2.88539008f * x);
    return 1.0f - 2.0f * RCPF(t + 1.0f);
}

// Gate-row mapping for thread t2 = W*64+L (W=wave, L=lane), sub-gate p in {0,1}:
//   row = (2*W + p)*64 + L   (W0 -> gates i,f ; W1 -> gates g,o)
__device__ __forceinline__ int gate_row(int t2, int p) {
    return (2 * (t2 >> 6) + p) * 64 + (t2 & 63);
}

// ---------------------------------------------------------------------------
// Kernel 1 (fused prep):
//  blocks [0,128):   proj[v][t2*2+p] = dot(emb[v], W_ih[gate_row(t2,p)]) + b_ih + b_hh
//  blocks [128,160): repack W_hh f32 -> half2: whh[t2*64 + p*32 + j] =
//                    (W_hh[gate_row(t2,p)][2j], [2j+1]) -- 256B/thread contiguous
//  block 128, tid 0 zeroes the loss accumulator.
// ---------------------------------------------------------------------------
__global__ void k_prep(const float* __restrict__ emb, const float* __restrict__ Wih,
                       const float* __restrict__ bih, const float* __restrict__ bhh,
                       const float* __restrict__ Whh,
                       float* __restrict__ proj, uint32_t* __restrict__ whh,
                       float* __restrict__ loss_slot) {
    int tid = threadIdx.x;  // 0..255
    if (blockIdx.x < V_) {
        int v = blockIdx.x;
        int t2 = tid >> 1, p = tid & 1;
        int row = gate_row(t2, p);
        const float4* e4 = (const float4*)(emb + v * E_);
        const float4* w4 = (const float4*)(Wih + row * E_);
        float acc = bih[row] + bhh[row];
#pragma unroll
        for (int i = 0; i < E_ / 4; ++i) {
            float4 a = e4[i];
            float4 b = w4[i];
            acc += a.x * b.x + a.y * b.y + a.z * b.z + a.w * b.w;
        }
        proj[v * G4_ + tid] = acc;
    } else {
        if (blockIdx.x == V_ && tid == 0) *loss_slot = 0.0f;
        int n = (blockIdx.x - V_) * 256 + tid;  // 0..8191
        int j = n & 31;
        int p = (n >> 5) & 1;
        int t2 = n >> 6;
        int row = gate_row(t2, p);
        half2_t h2 = {(half1)Whh[row * H_ + 2 * j], (half1)Whh[row * H_ + 2 * j + 1]};
        whh[n] = __builtin_bit_cast(uint32_t, h2);
    }
}

// ---------------------------------------------------------------------------
// Kernel 2: recurrence, gate-split across 2 waves. Block = 1 batch element.
// Thread (W,L): 64 half2 W_hh weights in VGPRs (2 gates x 32) -- half the
// R1-R3 array, sized to stay in arch VGPRs. Wave1 computes tanh(g),sigm(o)
// -> gbuf; wave0 owns c: c = f*c + i*g, h = o*tanh(c) -> hbuf (f16).
// 2 syncthreads per step; 4096 waves = 4/SIMD.
// ---------------------------------------------------------------------------
__global__ __launch_bounds__(128, 2)
void k_lstm(const int* __restrict__ x, const uint32_t* __restrict__ whh,
            const float* __restrict__ proj, const float* __restrict__ Wfc,
            const float* __restrict__ bfc, const float* __restrict__ targets,
            float* __restrict__ logits, float* __restrict__ loss_slot) {
    int b = blockIdx.x;
    int t2 = threadIdx.x;  // 0..127
    int W = t2 >> 6, L = t2 & 63;

    __shared__ __align__(16) uint32_t hbuf[32];  // 64 f16: h[0..63]
    __shared__ float2 gbuf[64];                  // (tanh(g), sigm(o)) per unit
    __shared__ int xrow[T_];

    xrow[t2] = x[b * T_ + t2];
    xrow[128 + t2] = x[b * T_ + 128 + t2];
    if (t2 < 32) hbuf[t2] = 0u;  // h0 = 0
    __syncthreads();

    // 64 half2 weights: w[j] = gate p=0 pair j, w[32+j] = gate p=1 pair j
    half2_t w[64];
    {
        const uint4* wb4 = (const uint4*)(whh + t2 * 64);
#pragma unroll
        for (int i = 0; i < 16; ++i) {
            uint4 q = wb4[i];
            w[4 * i + 0] = bchalf2(q.x);
            w[4 * i + 1] = bchalf2(q.y);
            w[4 * i + 2] = bchalf2(q.z);
            w[4 * i + 3] = bchalf2(q.w);
        }
    }

    float c = 0.0f, h = 0.0f;
    float2 pu = *(const float2*)(proj + xrow[0] * G4_ + t2 * 2);

    const uint4* hb4 = (const uint4*)hbuf;
    half1* hb16 = (half1*)hbuf;

    for (int t = 0; t < T_; ++t) {
        float2 pn = *(const float2*)(proj + xrow[(t + 1) & (T_ - 1)] * G4_ + t2 * 2);

        float a0 = pu.x, a1 = pu.y;  // accumulate gates (2W) and (2W+1)
#pragma unroll
        for (int q = 0; q < 8; ++q) {
            uint4 hh = hb4[q];  // broadcast ds_read_b128 (uniform address)
            half2_t h0 = bchalf2(hh.x), h1 = bchalf2(hh.y);
            half2_t h2 = bchalf2(hh.z), h3 = bchalf2(hh.w);
            a0 = fdot2(w[q * 4 + 0], h0, a0);
            a1 = fdot2(w[32 + q * 4 + 0], h0, a1);
            a0 = fdot2(w[q * 4 + 1], h1, a0);
            a1 = fdot2(w[32 + q * 4 + 1], h1, a1);
            a0 = fdot2(w[q * 4 + 2], h2, a0);
            a1 = fdot2(w[32 + q * 4 + 2], h2, a1);
            a0 = fdot2(w[q * 4 + 3], h3, a0);
            a1 = fdot2(w[32 + q * 4 + 3], h3, a1);
        }

        float i_, f_;
        if (W == 1) {  // wave-uniform branch
            float g_ = tanhr(a0);
            float o_ = sigm(a1);
            gbuf[L] = make_float2(g_, o_);
        } else {
            i_ = sigm(a0);
            f_ = sigm(a1);
        }
        __syncthreads();  // gbuf ready
        if (W == 0) {
            float2 go = gbuf[L];
            c = f_ * c + i_ * go.x;
            h = go.y * tanhr(c);
            hb16[L] = (half1)h;
        }
        __syncthreads();  // hbuf ready
        pu = pn;
    }

    // wave0 lane L holds h[L]: logits + fused loss term
    if (W == 0) {
        float contrib = h * Wfc[L];
#pragma unroll
        for (int off = 32; off > 0; off >>= 1) contrib += __shfl_down(contrib, off, 64);
        if (L == 0) {
            float z = contrib + bfc[0];
            logits[b] = z;
            float tg = targets[b];
            float e = EXP2F(-1.44269504f * fabsf(z));
            float lsp = fminf(z, 0.0f) - log1pf(e);
            float lsn = lsp - z;
            float term = -(POS_W * tg * lsp + (1.0f - tg) * lsn) * (1.0f / (float)B_);
            atomicAdd(loss_slot, term);
        }
    }
}

// ---------------------------------------------------------------------------
extern "C" void kernel_launch(void* const* d_in, const int* in_sizes, int n_in,
                              void* d_out, int out_size, void* d_ws, size_t ws_size,
                              hipStream_t stream) {
    const int* x = (const int*)d_in[0];
    const float* targets = (const float*)d_in[1];
    const float* emb = (const float*)d_in[2];
    const float* Wih = (const float*)d_in[3];
    const float* Whh = (const float*)d_in[4];
    const float* bih = (const float*)d_in[5];
    const float* bhh = (const float*)d_in[6];
    const float* Wfc = (const float*)d_in[7];
    const float* bfc = (const float*)d_in[8];
    float* out = (float*)d_out;  // [0..2047] logits, [2048] loss

    float* proj = (float*)d_ws;                               // 128*256*4 = 128 KiB
    uint32_t* whh = (uint32_t*)((char*)d_ws + 128 * 1024);    // 8192*4    = 32 KiB

    k_prep<<<dim3(V_ + 32), dim3(256), 0, stream>>>(emb, Wih, bih, bhh, Whh, proj, whh,
                                                    out + B_);
    k_lstm<<<dim3(B_), dim3(128), 0, stream>>>(x, whh, proj, Wfc, bfc, targets, out,
                                               out + B_);
}

// Round 5
// 215.214 us; speedup vs baseline: 1.3834x; 1.3834x over previous
//
#include <hip/hip_runtime.h>
#include <stdint.h>

#define B_ 2048
#define T_ 256
#define V_ 128
#define E_ 128
#define H_ 64
#define G4_ 256  // 4*H
#define POS_W 20.0f
#define MB_ 8            // batch rows per block (M=16 MFMA tile, rows 8..15 zero)
#define NBLK_ (B_ / MB_) // 256 blocks

typedef _Float16 half1;
typedef __attribute__((ext_vector_type(8))) _Float16 f16x8;
typedef __attribute__((ext_vector_type(4))) float f32x4;
typedef __attribute__((ext_vector_type(2))) float f32x2;

#if __has_builtin(__builtin_amdgcn_exp2f)
#define EXP2F(x) __builtin_amdgcn_exp2f(x)
#else
#define EXP2F(x) exp2f(x)
#endif

#if __has_builtin(__builtin_amdgcn_rcpf)
#define RCPF(x) __builtin_amdgcn_rcpf(x)
#else
#define RCPF(x) (1.0f / (x))
#endif

__device__ __forceinline__ float sigm(float x) {
    return RCPF(1.0f + EXP2F(-1.44269504f * x));
}
__device__ __forceinline__ float tanhr(float x) {
    // tanh(x) = 1 - 2/(e^(2x)+1); exp2 over/underflow saturates correctly
    float t = EXP2F(2.88539008f * x);
    return 1.0f - 2.0f * RCPF(t + 1.0f);
}

// ---------------------------------------------------------------------------
// k_prep:
//  blocks [0,128): projP[v][uu*8 + s]: s=[i0,i1,f0,f1,g0,g1,o0,o1] for units
//    u=2uu+(s&1): dot(emb[v], W_ih[gate*64+u]) + b_ih + b_hh   (f32, 128 KiB)
//  blocks [128,136): Bp MFMA B-fragments of W_hh (f16, 32 KiB):
//    group gidx=(w,jj,c,l): lane l of wave w, N-tile jj, K-chunk c holds
//    B[k=32c+8*(l>>4)+i][n=64w+16jj+(l&15)] = Whh[n][k] , i=0..7
//  block 128 tid 0 zeroes the loss slot.
// ---------------------------------------------------------------------------
__global__ void k_prep(const float* __restrict__ emb, const float* __restrict__ Wih,
                       const float* __restrict__ bih, const float* __restrict__ bhh,
                       const float* __restrict__ Whh,
                       float* __restrict__ projP, half1* __restrict__ Bp,
                       float* __restrict__ loss_slot) {
    int tid = threadIdx.x;  // 0..255
    if (blockIdx.x < V_) {
        int v = blockIdx.x;
        int s = tid & 7;
        int uu = tid >> 3;
        int gate = s >> 1;
        int u = 2 * uu + (s & 1);
        int row = gate * 64 + u;
        const float4* e4 = (const float4*)(emb + v * E_);
        const float4* w4 = (const float4*)(Wih + row * E_);
        float acc = bih[row] + bhh[row];
#pragma unroll
        for (int i = 0; i < E_ / 4; ++i) {
            float4 a = e4[i];
            float4 b = w4[i];
            acc += a.x * b.x + a.y * b.y + a.z * b.z + a.w * b.w;
        }
        projP[v * G4_ + tid] = acc;  // tid == uu*8+s, coalesced
    } else {
        if (blockIdx.x == V_ && tid == 0) *loss_slot = 0.0f;
        int gidx = (blockIdx.x - V_) * 256 + tid;  // 0..2047
        int l = gidx & 63;
        int c = (gidx >> 6) & 1;
        int jj = (gidx >> 7) & 3;
        int w = gidx >> 9;
        int n = 64 * w + 16 * jj + (l & 15);
        int kb = 32 * c + 8 * (l >> 4);
        half1 tmp[8];
#pragma unroll
        for (int i = 0; i < 8; ++i) tmp[i] = (half1)Whh[n * H_ + kb + i];
        *(f16x8*)(Bp + gidx * 8) = *(const f16x8*)tmp;
    }
}

// ---------------------------------------------------------------------------
// k_lstm: MFMA recurrence. Block = 8 batch rows, 256 thr (4 waves).
// Per step: A-frags (h, f16, LDS canonical layout) -> 8x mfma_f32_16x16x32_f16
// (B = W_hh frags, loop-invariant regs; AGPR residency is FREE for MFMA) ->
// raw gates to padded gbuf -> barrier -> thread (m,uu) updates units 2uu,2uu+1
// with prefetched projP -> h back to hf in A-frag layout -> barrier.
// ---------------------------------------------------------------------------
__launch_bounds__(256, 1)
__global__ void k_lstm(const int* __restrict__ x, const half1* __restrict__ Bp,
                       const float* __restrict__ projP, const float* __restrict__ Wfc,
                       const float* __restrict__ bfc, const float* __restrict__ targets,
                       float* __restrict__ logits, float* __restrict__ loss_slot) {
    int b0 = blockIdx.x * MB_;
    int t = threadIdx.x;          // 0..255
    int w = t >> 6, l = t & 63;   // wave, lane (MFMA roles)
    int m = t >> 5, uu = t & 31;  // update roles: batch row m, unit pair uu

    // hf: A-fragment buffer. f16 index = c*512 + lslot*8 + j, lslot = q*16+mrow,
    // holds h[mrow][k=32c+8q+j]. Rows mrow>=8 stay zero.
    __shared__ __align__(16) half1 hf[1024];
    __shared__ float gbuf[MB_][260];  // raw gates, padded stride (16B-aligned, bank-spread)
    __shared__ int xrow[MB_][T_];
    __shared__ float zred[MB_];

    // stage x (coalesced: consecutive t -> consecutive addresses)
#pragma unroll
    for (int i = 0; i < 8; ++i) xrow[m][uu + 32 * i] = x[(b0 + m) * T_ + uu + 32 * i];
    // zero hf (1024 f16 = 512 dwords)
    ((float*)hf)[t] = 0.0f;
    ((float*)hf)[t + 256] = 0.0f;
    __syncthreads();

    // loop-invariant B-fragments: 4 N-tiles x 2 K-chunks, 8 f16 each (32 regs)
    f16x8 bf[4][2];
#pragma unroll
    for (int jj = 0; jj < 4; ++jj)
#pragma unroll
        for (int c = 0; c < 2; ++c)
            bf[jj][c] = *(const f16x8*)(Bp + (((w * 4 + jj) * 2 + c) * 64 + l) * 8);

    float c0 = 0.0f, c1 = 0.0f, h0 = 0.0f, h1 = 0.0f;

    // prefetch projP for step 0
    int v0 = xrow[m][0];
    f32x4 ppa = *(const f32x4*)(projP + v0 * G4_ + uu * 8);
    f32x4 ppb = *(const f32x4*)(projP + v0 * G4_ + uu * 8 + 4);

    for (int step = 0; step < T_; ++step) {
        // ---- phase 1: A-frags (canonical lane-contiguous b128, conflict-free)
        f16x8 a0 = *(const f16x8*)(hf + l * 8);
        f16x8 a1 = *(const f16x8*)(hf + 512 + l * 8);

        // ---- phase 2: gates[m][n] = sum_k h[m][k] * Whh[n][k]
        f32x4 dd[4];
#pragma unroll
        for (int jj = 0; jj < 4; ++jj) {
            f32x4 z4 = {0.0f, 0.0f, 0.0f, 0.0f};
            f32x4 d = __builtin_amdgcn_mfma_f32_16x16x32_f16(a0, bf[jj][0], z4, 0, 0, 0);
            dd[jj] = __builtin_amdgcn_mfma_f32_16x16x32_f16(a1, bf[jj][1], d, 0, 0, 0);
        }

        // ---- phase 3: store valid rows (m<8 -> lanes 0..31) to gbuf
        if (l < 32) {
            int r0 = (l >> 4) * 4;
            int colb = w * 64 + (l & 15);
#pragma unroll
            for (int jj = 0; jj < 4; ++jj) {
#pragma unroll
                for (int r = 0; r < 4; ++r) gbuf[r0 + r][colb + 16 * jj] = dd[jj][r];
            }
        }
        __syncthreads();  // barrier A: gbuf ready; also protects hf WAR

        // issue next step's projP prefetch first (L2 latency overlaps nonlin)
        int vn = xrow[m][(step + 1) & (T_ - 1)];
        f32x4 pna = *(const f32x4*)(projP + vn * G4_ + uu * 8);
        f32x4 pnb = *(const f32x4*)(projP + vn * G4_ + uu * 8 + 4);

        // ---- phase 5: update units u0=2uu, u1=2uu+1 of batch row m
        f32x2 gi = *(const f32x2*)&gbuf[m][2 * uu];
        f32x2 gf = *(const f32x2*)&gbuf[m][64 + 2 * uu];
        f32x2 gg = *(const f32x2*)&gbuf[m][128 + 2 * uu];
        f32x2 go = *(const f32x2*)&gbuf[m][192 + 2 * uu];

        float i0 = sigm(gi.x + ppa.x), i1 = sigm(gi.y + ppa.y);
        float f0 = sigm(gf.x + ppa.z), f1 = sigm(gf.y + ppa.w);
        float g0 = tanhr(gg.x + ppb.x), g1 = tanhr(gg.y + ppb.y);
        float o0 = sigm(go.x + ppb.z), o1 = sigm(go.y + ppb.w);
        c0 = f0 * c0 + i0 * g0;
        h0 = o0 * tanhr(c0);
        c1 = f1 * c1 + i1 * g1;
        h1 = o1 * tanhr(c1);

        // h pair -> hf in A-frag layout: u0 even => (j, j+1) in one slot
        {
            int u0 = 2 * uu;
            int cc = u0 >> 5, q = (u0 >> 3) & 3, j = u0 & 7;
            half1* dst = hf + cc * 512 + (q * 16 + m) * 8 + j;
            dst[0] = (half1)h0;
            dst[1] = (half1)h1;
        }
        ppa = pna;
        ppb = pnb;
        __syncthreads();  // barrier B: hf ready for next step
    }

    // epilogue: logits + loss. Thread (m,uu) holds h_T for units 2uu, 2uu+1.
    float part = h0 * Wfc[2 * uu] + h1 * Wfc[2 * uu + 1];
#pragma unroll
    for (int off = 16; off > 0; off >>= 1) part += __shfl_down(part, off, 32);
    if (uu == 0) {
        float z = part + bfc[0];
        logits[b0 + m] = z;
        float tg = targets[b0 + m];
        float e = EXP2F(-1.44269504f * fabsf(z));
        float lsp = fminf(z, 0.0f) - log1pf(e);
        float lsn = lsp - z;
        zred[m] = -(POS_W * tg * lsp + (1.0f - tg) * lsn) * (1.0f / (float)B_);
    }
    __syncthreads();
    if (t == 0) {
        float s = 0.0f;
#pragma unroll
        for (int i = 0; i < MB_; ++i) s += zred[i];
        atomicAdd(loss_slot, s);  // 256 atomics total
    }
}

// ---------------------------------------------------------------------------
extern "C" void kernel_launch(void* const* d_in, const int* in_sizes, int n_in,
                              void* d_out, int out_size, void* d_ws, size_t ws_size,
                              hipStream_t stream) {
    const int* x = (const int*)d_in[0];
    const float* targets = (const float*)d_in[1];
    const float* emb = (const float*)d_in[2];
    const float* Wih = (const float*)d_in[3];
    const float* Whh = (const float*)d_in[4];
    const float* bih = (const float*)d_in[5];
    const float* bhh = (const float*)d_in[6];
    const float* Wfc = (const float*)d_in[7];
    const float* bfc = (const float*)d_in[8];
    float* out = (float*)d_out;  // [0..2047] logits, [2048] loss

    float* projP = (float*)d_ws;                            // 128*256*4 = 128 KiB
    half1* Bp = (half1*)((char*)d_ws + 128 * 1024);         // 2048*8*2  = 32 KiB

    k_prep<<<dim3(V_ + 8), dim3(256), 0, stream>>>(emb, Wih, bih, bhh, Whh, projP, Bp,
                                                   out + B_);
    k_lstm<<<dim3(NBLK_), dim3(256), 0, stream>>>(x, Bp, projP, Wfc, bfc, targets, out,
                                                  out + B_);
}

// Round 6
// 215.152 us; speedup vs baseline: 1.3838x; 1.0003x over previous
//
#include <hip/hip_runtime.h>
#include <stdint.h>

#define B_ 2048
#define T_ 256
#define V_ 128
#define E_ 128
#define H_ 64
#define G4_ 256  // 4*H
#define POS_W 20.0f
#define MB_ 8            // batch rows per block (M=16 MFMA tile, rows 8..15 unused)
#define NBLK_ (B_ / MB_) // 256 blocks

typedef _Float16 half1;
typedef __attribute__((ext_vector_type(8))) _Float16 f16x8;
typedef __attribute__((ext_vector_type(4))) float f32x4;

#if __has_builtin(__builtin_amdgcn_exp2f)
#define EXP2F(x) __builtin_amdgcn_exp2f(x)
#else
#define EXP2F(x) exp2f(x)
#endif

#if __has_builtin(__builtin_amdgcn_rcpf)
#define RCPF(x) __builtin_amdgcn_rcpf(x)
#else
#define RCPF(x) (1.0f / (x))
#endif

__device__ __forceinline__ float sigm(float x) {
    return RCPF(1.0f + EXP2F(-1.44269504f * x));
}
__device__ __forceinline__ float tanhr(float x) {
    // tanh(x) = 1 - 2/(e^(2x)+1); exp2 over/underflow saturates correctly
    float t = EXP2F(2.88539008f * x);
    return 1.0f - 2.0f * RCPF(t + 1.0f);
}

// ---------------------------------------------------------------------------
// k_prep: projC[v][u][g] = dot(emb[v], W_ih[g*64+u]) + b_ih + b_hh   (f32)
// Layout [v][unit][gate] so the LSTM kernel gathers one float4 per (v,unit).
// Block 0 / tid 0 zeroes the loss accumulator.
// ---------------------------------------------------------------------------
__global__ void k_prep(const float* __restrict__ emb, const float* __restrict__ Wih,
                       const float* __restrict__ bih, const float* __restrict__ bhh,
                       float* __restrict__ projC, float* __restrict__ loss_slot) {
    int tid = threadIdx.x;  // 0..255; u = tid>>2, g = tid&3
    int v = blockIdx.x;
    if (v == 0 && tid == 0) *loss_slot = 0.0f;
    int u = tid >> 2, g = tid & 3;
    int row = g * 64 + u;
    const float4* e4 = (const float4*)(emb + v * E_);
    const float4* w4 = (const float4*)(Wih + row * E_);
    float acc = bih[row] + bhh[row];
#pragma unroll
    for (int i = 0; i < E_ / 4; ++i) {
        float4 a = e4[i];
        float4 b = w4[i];
        acc += a.x * b.x + a.y * b.y + a.z * b.z + a.w * b.w;
    }
    projC[v * G4_ + tid] = acc;  // coalesced
}

// ---------------------------------------------------------------------------
// k_lstm: MFMA recurrence with gate-permuted B. Block = 8 batch rows, 4 waves.
// B-permutation: wave w's N-tile jj holds W_hh rows jj*64 + 16w + c  (c=tile
// col), so after MFMA lane l owns ALL 4 gates of unit u=16w+(l&15) for rows
// (l>>4)*4+r -- gates never round-trip through LDS. __shfl_xor(32) rebalances
// rows 2,3/6,7 to the upper half-wave: every lane updates exactly 2 (row,unit)
// elements. h goes back via a double-buffered A-layout LDS buffer -> ONE
// barrier per step. proj gathered from L2 one step ahead ([v][u][g] float4).
// ---------------------------------------------------------------------------
__launch_bounds__(256, 1)
__global__ void k_lstm(const int* __restrict__ x, const float* __restrict__ Whh,
                       const float* __restrict__ projC, const float* __restrict__ Wfc,
                       const float* __restrict__ bfc, const float* __restrict__ targets,
                       float* __restrict__ logits, float* __restrict__ loss_slot) {
    int b0 = blockIdx.x * MB_;
    int t = threadIdx.x;         // 0..255
    int w = t >> 6, l = t & 63;  // wave, lane
    int q = l >> 4, cc = l & 15;
    int u = 16 * w + cc;                       // unit owned by this lane
    int ra = (q < 2) ? 4 * q : 4 * (q - 2) + 2;  // rows {ra, ra+1} after swizzle
    int rb = ra + 1;
    bool hiq = (q >= 2);

    __shared__ __align__(16) half1 hf[2][1024];  // A-layout h, double-buffered
    __shared__ int xT[T_][8];                    // transposed token indices
    __shared__ float hfin[MB_][68];              // final h (padded)
    __shared__ float zred[MB_];

    // stage xT (coalesced global reads: fixed i, consecutive t)
#pragma unroll
    for (int i = 0; i < MB_; ++i) xT[t][i] = x[(b0 + i) * T_ + t];
    // zero both hf buffers (1024 dwords total)
    ((float*)hf)[t] = 0.0f;
    ((float*)hf)[t + 256] = 0.0f;
    ((float*)hf)[t + 512] = 0.0f;
    ((float*)hf)[t + 768] = 0.0f;
    __syncthreads();

    // Build B-fragments inline from W_hh (f32 in L2): N-tile jj, K-chunk c.
    // frag element j: B[k = c*32 + q*8 + j][n-col cc] = Whh[jj*64+16w+cc][k]
    f16x8 bf[4][2];
#pragma unroll
    for (int jj = 0; jj < 4; ++jj) {
#pragma unroll
        for (int c = 0; c < 2; ++c) {
            int row = jj * 64 + 16 * w + cc;
            int kb = c * 32 + q * 8;
            float4 w0 = *(const float4*)(Whh + row * H_ + kb);
            float4 w1 = *(const float4*)(Whh + row * H_ + kb + 4);
            f16x8 tmp;
            tmp[0] = (half1)w0.x; tmp[1] = (half1)w0.y;
            tmp[2] = (half1)w0.z; tmp[3] = (half1)w0.w;
            tmp[4] = (half1)w1.x; tmp[5] = (half1)w1.y;
            tmp[6] = (half1)w1.z; tmp[7] = (half1)w1.w;
            bf[jj][c] = tmp;
        }
    }

    // h-write base for unit u in A-layout: f16 idx = (u>>5)*512 + (((u>>3)&3)*16+m)*8 + (u&7)
    int hbase = (u >> 5) * 512 + ((u >> 3) & 3) * 128 + (u & 7);

    float cA = 0.0f, cB = 0.0f, hA = 0.0f, hB = 0.0f;

    // prefetch proj for step 0 (rows ra, rb share a b64 token read)
    int2 v01 = *(const int2*)&xT[0][ra];
    f32x4 ppA = *(const f32x4*)(projC + v01.x * G4_ + u * 4);
    f32x4 ppB = *(const f32x4*)(projC + v01.y * G4_ + u * 4);

    int p = 0;
    for (int step = 0; step < T_; ++step) {
        // A-fragments of h_t (conflict-free lane-contiguous b128)
        const f16x8 a0 = *(const f16x8*)(hf[p] + l * 8);
        const f16x8 a1 = *(const f16x8*)(hf[p] + 512 + l * 8);

        // prefetch next step's proj (consumed next iteration)
        int2 vn = *(const int2*)&xT[(step + 1) & (T_ - 1)][ra];
        f32x4 pnA = *(const f32x4*)(projC + vn.x * G4_ + u * 4);
        f32x4 pnB = *(const f32x4*)(projC + vn.y * G4_ + u * 4);

        // gates[m][gate jj of unit u] for rows m = q*4 + r
        f32x4 z4 = {0.0f, 0.0f, 0.0f, 0.0f};
        f32x4 dd[4];
#pragma unroll
        for (int jj = 0; jj < 4; ++jj) {
            f32x4 d0 = __builtin_amdgcn_mfma_f32_16x16x32_f16(a0, bf[jj][0], z4, 0, 0, 0);
            dd[jj] = __builtin_amdgcn_mfma_f32_16x16x32_f16(a1, bf[jj][1], d0, 0, 0, 0);
        }

        // rebalance: rows {2,3}/{6,7} move to upper half-wave lanes
        float gA[4], gB[4];
#pragma unroll
        for (int jj = 0; jj < 4; ++jj) {
            float s2 = __shfl_xor(dd[jj][2], 32, 64);
            float s3 = __shfl_xor(dd[jj][3], 32, 64);
            gA[jj] = hiq ? s2 : dd[jj][0];
            gB[jj] = hiq ? s3 : dd[jj][1];
        }

        // LSTM cell update for (row ra, u) and (row rb, u)
        float iA = sigm(gA[0] + ppA.x);
        float fA = sigm(gA[1] + ppA.y);
        float ggA = tanhr(gA[2] + ppA.z);
        float oA = sigm(gA[3] + ppA.w);
        cA = fA * cA + iA * ggA;
        hA = oA * tanhr(cA);

        float iB = sigm(gB[0] + ppB.x);
        float fB = sigm(gB[1] + ppB.y);
        float ggB = tanhr(gB[2] + ppB.z);
        float oB = sigm(gB[3] + ppB.w);
        cB = fB * cB + iB * ggB;
        hB = oB * tanhr(cB);

        // publish h_{t+1} into the other buffer (A-layout), then ONE barrier
        half1* hw = hf[p ^ 1] + hbase;
        hw[ra * 8] = (half1)hA;
        hw[rb * 8] = (half1)hB;

        ppA = pnA;
        ppB = pnB;
        p ^= 1;
        __syncthreads();
    }

    // epilogue: logits + fused loss
    hfin[ra][u] = hA;
    hfin[rb][u] = hB;
    __syncthreads();
    int m8 = t >> 5, uu = t & 31;
    float part = hfin[m8][2 * uu] * Wfc[2 * uu] + hfin[m8][2 * uu + 1] * Wfc[2 * uu + 1];
#pragma unroll
    for (int off = 16; off > 0; off >>= 1) part += __shfl_down(part, off, 32);
    if (uu == 0) {
        float z = part + bfc[0];
        logits[b0 + m8] = z;
        float tg = targets[b0 + m8];
        float e = EXP2F(-1.44269504f * fabsf(z));
        float lsp = fminf(z, 0.0f) - log1pf(e);
        float lsn = lsp - z;
        zred[m8] = -(POS_W * tg * lsp + (1.0f - tg) * lsn) * (1.0f / (float)B_);
    }
    __syncthreads();
    if (t == 0) {
        float s = 0.0f;
#pragma unroll
        for (int i = 0; i < MB_; ++i) s += zred[i];
        atomicAdd(loss_slot, s);
    }
}

// ---------------------------------------------------------------------------
extern "C" void kernel_launch(void* const* d_in, const int* in_sizes, int n_in,
                              void* d_out, int out_size, void* d_ws, size_t ws_size,
                              hipStream_t stream) {
    const int* x = (const int*)d_in[0];
    const float* targets = (const float*)d_in[1];
    const float* emb = (const float*)d_in[2];
    const float* Wih = (const float*)d_in[3];
    const float* Whh = (const float*)d_in[4];
    const float* bih = (const float*)d_in[5];
    const float* bhh = (const float*)d_in[6];
    const float* Wfc = (const float*)d_in[7];
    const float* bfc = (const float*)d_in[8];
    float* out = (float*)d_out;  // [0..2047] logits, [2048] loss

    float* projC = (float*)d_ws;  // 128*256*4 = 128 KiB

    k_prep<<<dim3(V_), dim3(256), 0, stream>>>(emb, Wih, bih, bhh, projC, out + B_);
    k_lstm<<<dim3(NBLK_), dim3(256), 0, stream>>>(x, Whh, projC, Wfc, bfc, targets, out,
                                                  out + B_);
}

// Round 7
// 172.162 us; speedup vs baseline: 1.7293x; 1.2497x over previous
//
#include <hip/hip_runtime.h>
#include <stdint.h>

#define B_ 2048
#define T_ 256
#define V_ 128
#define E_ 128
#define H_ 64
#define G4_ 256  // 4*H
#define POS_W 20.0f
#define MB_ 8            // batch rows per block (M=16 tile, rows {4q+2,4q+3} unused)
#define NBLK_ (B_ / MB_) // 256 blocks

typedef _Float16 half1;
typedef __attribute__((ext_vector_type(8))) _Float16 f16x8;
typedef __attribute__((ext_vector_type(4))) float f32x4;

#if __has_builtin(__builtin_amdgcn_exp2f)
#define EXP2F(x) __builtin_amdgcn_exp2f(x)
#else
#define EXP2F(x) exp2f(x)
#endif

#if __has_builtin(__builtin_amdgcn_rcpf)
#define RCPF(x) __builtin_amdgcn_rcpf(x)
#else
#define RCPF(x) (1.0f / (x))
#endif

__device__ __forceinline__ float sigm(float x) {
    return RCPF(1.0f + EXP2F(-1.44269504f * x));
}
__device__ __forceinline__ float tanhr(float x) {
    // tanh(x) = 1 - 2/(e^(2x)+1); exp2 over/underflow saturates correctly
    float t = EXP2F(2.88539008f * x);
    return 1.0f - 2.0f * RCPF(t + 1.0f);
}

// Barrier that drains ONLY lgkmcnt (LDS ordering) and leaves vmcnt in flight.
// __syncthreads() would emit s_waitcnt vmcnt(0) before s_barrier, putting the
// L2 proj-prefetch latency on the per-step critical path (R5/R6: both 1422
// cyc/step for this reason). Safe here: h-exchange is double-buffered (no WAR
// across the barrier) and in-flight global loads only write registers.
__device__ __forceinline__ void lds_barrier() {
    asm volatile("s_waitcnt lgkmcnt(0)\n\ts_barrier" ::: "memory");
}

// ---------------------------------------------------------------------------
// k_prep: projC[v][u][g] = dot(emb[v], W_ih[g*64+u]) + b_ih + b_hh   (f32)
// Layout [v][unit][gate]: LSTM kernel gathers one float4 per (v,unit).
// Block 0 / tid 0 zeroes the loss accumulator.
// ---------------------------------------------------------------------------
__global__ void k_prep(const float* __restrict__ emb, const float* __restrict__ Wih,
                       const float* __restrict__ bih, const float* __restrict__ bhh,
                       float* __restrict__ projC, float* __restrict__ loss_slot) {
    int tid = threadIdx.x;  // 0..255; u = tid>>2, g = tid&3
    int v = blockIdx.x;
    if (v == 0 && tid == 0) *loss_slot = 0.0f;
    int u = tid >> 2, g = tid & 3;
    int row = g * 64 + u;
    const float4* e4 = (const float4*)(emb + v * E_);
    const float4* w4 = (const float4*)(Wih + row * E_);
    float acc = bih[row] + bhh[row];
#pragma unroll
    for (int i = 0; i < E_ / 4; ++i) {
        float4 a = e4[i];
        float4 b = w4[i];
        acc += a.x * b.x + a.y * b.y + a.z * b.z + a.w * b.w;
    }
    projC[v * G4_ + tid] = acc;  // coalesced
}

// ---------------------------------------------------------------------------
// k_lstm: MFMA recurrence, gate-permuted B, shuffle-free row placement.
// Block = 8 batch rows (4 waves). Batch row rr lives at M-row 4*(rr>>1)+(rr&1),
// so lane (q,cc) of wave w owns cells (rows 2q,2q+1) x unit u=16w+cc directly
// in C-regs [0],[1] -- zero cross-lane traffic. h returns via double-buffered
// A-layout LDS; ONE lgkm-only barrier per step; projC gathered from L2 at
// prefetch depth 2 (never waited on the step path).
// ---------------------------------------------------------------------------
__launch_bounds__(256, 1)
__global__ void k_lstm(const int* __restrict__ x, const float* __restrict__ Whh,
                       const float* __restrict__ projC, const float* __restrict__ Wfc,
                       const float* __restrict__ bfc, const float* __restrict__ targets,
                       float* __restrict__ logits, float* __restrict__ loss_slot) {
    int b0 = blockIdx.x * MB_;
    int t = threadIdx.x;         // 0..255
    int w = t >> 6, l = t & 63;  // wave, lane
    int q = l >> 4, cc = l & 15;
    int u = 16 * w + cc;   // unit owned by this lane (all 4 gates)
    int rA = 2 * q;        // batch rows owned: rA, rA+1  (M-rows 4q, 4q+1)

    __shared__ __align__(16) half1 hf[2][1024];  // A-layout h, double-buffered
    __shared__ int xT[T_][8];                    // transposed token indices
    __shared__ float hfin[MB_][68];              // final h (padded)
    __shared__ float zred[MB_];

    // stage xT (coalesced: fixed i, consecutive t)
#pragma unroll
    for (int i = 0; i < MB_; ++i) xT[t][i] = x[(b0 + i) * T_ + t];
    ((float*)hf)[t] = 0.0f;
    ((float*)hf)[t + 256] = 0.0f;
    ((float*)hf)[t + 512] = 0.0f;
    ((float*)hf)[t + 768] = 0.0f;
    __syncthreads();

    // B-fragments inline from W_hh (f32, L2): N-tile jj, K-chunk c.
    // frag elem j: B[k=c*32+q*8+j][col cc] = Whh[jj*64+16w+cc][k]  (R5/R6-verified)
    f16x8 bf[4][2];
#pragma unroll
    for (int jj = 0; jj < 4; ++jj) {
#pragma unroll
        for (int c = 0; c < 2; ++c) {
            int row = jj * 64 + 16 * w + cc;
            int kb = c * 32 + q * 8;
            float4 w0 = *(const float4*)(Whh + row * H_ + kb);
            float4 w1 = *(const float4*)(Whh + row * H_ + kb + 4);
            f16x8 tmp;
            tmp[0] = (half1)w0.x; tmp[1] = (half1)w0.y;
            tmp[2] = (half1)w0.z; tmp[3] = (half1)w0.w;
            tmp[4] = (half1)w1.x; tmp[5] = (half1)w1.y;
            tmp[6] = (half1)w1.z; tmp[7] = (half1)w1.w;
            bf[jj][c] = tmp;
        }
    }

    // h-write base for unit u, M-row m: hf idx = (u>>5)*512 + ((u>>3)&3)*128 + m*8 + (u&7)
    int hbase = (u >> 5) * 512 + ((u >> 3) & 3) * 128 + (u & 7) + (4 * q) * 8;
    // A-read offsets: lane l reads 8 f16 at l*8 (chunk 0) and 512+l*8 (chunk 1)

    float cA = 0.0f, cB = 0.0f, hA = 0.0f, hB = 0.0f;

    // prefetch proj for steps 0 and 1 (depth 2)
    int2 v0 = *(const int2*)&xT[0][rA];
    int2 v1 = *(const int2*)&xT[1][rA];
    f32x4 ppA = *(const f32x4*)(projC + v0.x * G4_ + u * 4);
    f32x4 ppB = *(const f32x4*)(projC + v0.y * G4_ + u * 4);
    f32x4 pnA = *(const f32x4*)(projC + v1.x * G4_ + u * 4);
    f32x4 pnB = *(const f32x4*)(projC + v1.y * G4_ + u * 4);

    int p = 0;
#pragma unroll 2
    for (int step = 0; step < T_; ++step) {
        // issue depth-2 prefetch (consumed at step+2; wraps harmlessly at tail)
        int2 v2 = *(const int2*)&xT[(step + 2) & (T_ - 1)][rA];
        f32x4 p2A = *(const f32x4*)(projC + v2.x * G4_ + u * 4);
        f32x4 p2B = *(const f32x4*)(projC + v2.y * G4_ + u * 4);

        // A-fragments of h_t (conflict-free lane-contiguous b128)
        const f16x8 a0 = *(const f16x8*)(hf[p] + l * 8);
        const f16x8 a1 = *(const f16x8*)(hf[p] + 512 + l * 8);

        // gates: split accumulators (independent MFMAs), combine elems 0,1 only
        f32x4 z4 = {0.0f, 0.0f, 0.0f, 0.0f};
        float gA[4], gB[4];
#pragma unroll
        for (int jj = 0; jj < 4; ++jj) {
            f32x4 d0 = __builtin_amdgcn_mfma_f32_16x16x32_f16(a0, bf[jj][0], z4, 0, 0, 0);
            f32x4 d1 = __builtin_amdgcn_mfma_f32_16x16x32_f16(a1, bf[jj][1], z4, 0, 0, 0);
            gA[jj] = d0[0] + d1[0];
            gB[jj] = d0[1] + d1[1];
        }

        // cell updates for (row rA, u) and (row rA+1, u); pp loaded 2 steps ago
        float iA = sigm(gA[0] + ppA.x);
        float fA = sigm(gA[1] + ppA.y);
        float ggA = tanhr(gA[2] + ppA.z);
        float oA = sigm(gA[3] + ppA.w);
        cA = fA * cA + iA * ggA;
        hA = oA * tanhr(cA);

        float iB = sigm(gB[0] + ppB.x);
        float fB = sigm(gB[1] + ppB.y);
        float ggB = tanhr(gB[2] + ppB.z);
        float oB = sigm(gB[3] + ppB.w);
        cB = fB * cB + iB * ggB;
        hB = oB * tanhr(cB);

        // publish h_{t+1} (A-layout, other buffer): M-rows 4q, 4q+1
        half1* hw = hf[p ^ 1] + hbase;
        hw[0] = (half1)hA;
        hw[8] = (half1)hB;

        ppA = pnA; ppB = pnB;
        pnA = p2A; pnB = p2B;
        p ^= 1;
        lds_barrier();  // lgkmcnt-only: proj prefetches stay in flight
    }

    // epilogue: logits + fused loss
    hfin[rA][u] = hA;
    hfin[rA + 1][u] = hB;
    __syncthreads();
    int m8 = t >> 5, uu = t & 31;
    float part = hfin[m8][2 * uu] * Wfc[2 * uu] + hfin[m8][2 * uu + 1] * Wfc[2 * uu + 1];
#pragma unroll
    for (int off = 16; off > 0; off >>= 1) part += __shfl_down(part, off, 32);
    if (uu == 0) {
        float z = part + bfc[0];
        logits[b0 + m8] = z;
        float tg = targets[b0 + m8];
        float e = EXP2F(-1.44269504f * fabsf(z));
        float lsp = fminf(z, 0.0f) - log1pf(e);
        float lsn = lsp - z;
        zred[m8] = -(POS_W * tg * lsp + (1.0f - tg) * lsn) * (1.0f / (float)B_);
    }
    __syncthreads();
    if (t == 0) {
        float s = 0.0f;
#pragma unroll
        for (int i = 0; i < MB_; ++i) s += zred[i];
        atomicAdd(loss_slot, s);
    }
}

// ---------------------------------------------------------------------------
extern "C" void kernel_launch(void* const* d_in, const int* in_sizes, int n_in,
                              void* d_out, int out_size, void* d_ws, size_t ws_size,
                              hipStream_t stream) {
    const int* x = (const int*)d_in[0];
    const float* targets = (const float*)d_in[1];
    const float* emb = (const float*)d_in[2];
    const float* Wih = (const float*)d_in[3];
    const float* Whh = (const float*)d_in[4];
    const float* bih = (const float*)d_in[5];
    const float* bhh = (const float*)d_in[6];
    const float* Wfc = (const float*)d_in[7];
    const float* bfc = (const float*)d_in[8];
    float* out = (float*)d_out;  // [0..2047] logits, [2048] loss

    float* projC = (float*)d_ws;  // 128*256*4 = 128 KiB

    k_prep<<<dim3(V_), dim3(256), 0, stream>>>(emb, Wih, bih, bhh, projC, out + B_);
    k_lstm<<<dim3(NBLK_), dim3(256), 0, stream>>>(x, Whh, projC, Wfc, bfc, targets, out,
                                                  out + B_);
}

// Round 8
// 163.480 us; speedup vs baseline: 1.8212x; 1.0531x over previous
//
#include <hip/hip_runtime.h>
#include <stdint.h>

#define B_ 2048
#define T_ 256
#define V_ 128
#define E_ 128
#define H_ 64
#define G4_ 256  // 4*H
#define POS_W 20.0f
#define MB_ 4            // batch rows per block: row j at M-row 4j (C-reg[0] of lane quad j)
#define NBLK_ (B_ / MB_) // 512 blocks = 2 blocks/CU = 2 waves/SIMD
typedef _Float16 half1;
typedef __attribute__((ext_vector_type(8))) _Float16 f16x8;
typedef __attribute__((ext_vector_type(4))) float f32x4;

#if __has_builtin(__builtin_amdgcn_exp2f)
#define EXP2F(x) __builtin_amdgcn_exp2f(x)
#else
#define EXP2F(x) exp2f(x)
#endif

#if __has_builtin(__builtin_amdgcn_rcpf)
#define RCPF(x) __builtin_amdgcn_rcpf(x)
#else
#define RCPF(x) (1.0f / (x))
#endif

__device__ __forceinline__ float sigm(float x) {
    return RCPF(1.0f + EXP2F(-1.44269504f * x));
}
__device__ __forceinline__ float tanhr(float x) {
    // tanh(x) = 1 - 2/(e^(2x)+1); exp2 over/underflow saturates correctly
    float t = EXP2F(2.88539008f * x);
    return 1.0f - 2.0f * RCPF(t + 1.0f);
}

// Barrier draining ONLY lgkmcnt: keeps L2 proj-prefetches (vmcnt) in flight
// across the step boundary. R6->R7: removing the vmcnt drain from the step
// path cut 1422 -> 1000 cyc/step. Safe: h-exchange is double-buffered, and
// in-flight global loads only write registers.
__device__ __forceinline__ void lds_barrier() {
    asm volatile("s_waitcnt lgkmcnt(0)\n\ts_barrier" ::: "memory");
}

// ---------------------------------------------------------------------------
// k_prep: projC[v][u][g] = dot(emb[v], W_ih[g*64+u]) + b_ih + b_hh   (f32)
// Layout [v][unit][gate]: LSTM kernel gathers one float4 per (v,unit).
// Block 0 / tid 0 zeroes the loss accumulator.
// ---------------------------------------------------------------------------
__global__ void k_prep(const float* __restrict__ emb, const float* __restrict__ Wih,
                       const float* __restrict__ bih, const float* __restrict__ bhh,
                       float* __restrict__ projC, float* __restrict__ loss_slot) {
    int tid = threadIdx.x;  // 0..255; u = tid>>2, g = tid&3
    int v = blockIdx.x;
    if (v == 0 && tid == 0) *loss_slot = 0.0f;
    int u = tid >> 2, g = tid & 3;
    int row = g * 64 + u;
    const float4* e4 = (const float4*)(emb + v * E_);
    const float4* w4 = (const float4*)(Wih + row * E_);
    float acc = bih[row] + bhh[row];
#pragma unroll
    for (int i = 0; i < E_ / 4; ++i) {
        float4 a = e4[i];
        float4 b = w4[i];
        acc += a.x * b.x + a.y * b.y + a.z * b.z + a.w * b.w;
    }
    projC[v * G4_ + tid] = acc;  // coalesced
}

// ---------------------------------------------------------------------------
// k_lstm: MFMA recurrence, gate-permuted B, 1 cell per thread.
// Block = 4 batch rows (4 waves, 512 blocks total -> 2 waves/SIMD so
// independent blocks hide each other's LDS/MFMA/transcendental latency).
// Batch row j sits at M-row 4j: lane (q,cc) of wave w owns cell
// (row q, unit u=16w+cc) in C-reg[0] -- zero cross-lane traffic.
// h returns via double-buffered A-layout LDS; ONE lgkm-only barrier/step;
// projC prefetched from L2 at depth 2 (never waited on the step path).
// ---------------------------------------------------------------------------
__launch_bounds__(256, 2)
__global__ void k_lstm(const int* __restrict__ x, const float* __restrict__ Whh,
                       const float* __restrict__ projC, const float* __restrict__ Wfc,
                       const float* __restrict__ bfc, const float* __restrict__ targets,
                       float* __restrict__ logits, float* __restrict__ loss_slot) {
    int b0 = blockIdx.x * MB_;
    int t = threadIdx.x;         // 0..255
    int w = t >> 6, l = t & 63;  // wave, lane
    int q = l >> 4, cc = l & 15;
    int u = 16 * w + cc;  // unit owned by this lane (all 4 gates), batch row q

    __shared__ __align__(16) half1 hf[2][1024];  // A-layout h, double-buffered
    __shared__ int xT[T_][MB_];                  // transposed token indices
    __shared__ float hfin[MB_][68];              // final h (padded)
    __shared__ float zred[MB_];

    // stage xT (coalesced: fixed i, consecutive t)
#pragma unroll
    for (int i = 0; i < MB_; ++i) xT[t][i] = x[(b0 + i) * T_ + t];
    ((float*)hf)[t] = 0.0f;
    ((float*)hf)[t + 256] = 0.0f;
    ((float*)hf)[t + 512] = 0.0f;
    ((float*)hf)[t + 768] = 0.0f;
    __syncthreads();

    // B-fragments inline from W_hh (f32, L2): N-tile jj, K-chunk c.
    // frag elem j: B[k=c*32+q*8+j][col cc] = Whh[jj*64+16w+cc][k]  (R5-R7 verified)
    f16x8 bf[4][2];
#pragma unroll
    for (int jj = 0; jj < 4; ++jj) {
#pragma unroll
        for (int c = 0; c < 2; ++c) {
            int row = jj * 64 + 16 * w + cc;
            int kb = c * 32 + q * 8;
            float4 w0 = *(const float4*)(Whh + row * H_ + kb);
            float4 w1 = *(const float4*)(Whh + row * H_ + kb + 4);
            f16x8 tmp;
            tmp[0] = (half1)w0.x; tmp[1] = (half1)w0.y;
            tmp[2] = (half1)w0.z; tmp[3] = (half1)w0.w;
            tmp[4] = (half1)w1.x; tmp[5] = (half1)w1.y;
            tmp[6] = (half1)w1.z; tmp[7] = (half1)w1.w;
            bf[jj][c] = tmp;
        }
    }

    // h-write slot for (unit u, M-row 4q):
    // f16 idx = (u>>5)*512 + ((u>>3)&3)*128 + (4q)*8 + (u&7)
    int hbase = (u >> 5) * 512 + ((u >> 3) & 3) * 128 + (4 * q) * 8 + (u & 7);

    float cA = 0.0f, hA = 0.0f;

    // prefetch proj for steps 0 and 1 (depth 2); same-q lanes broadcast-read xT
    f32x4 ppA = *(const f32x4*)(projC + xT[0][q] * G4_ + u * 4);
    f32x4 pnA = *(const f32x4*)(projC + xT[1][q] * G4_ + u * 4);

    int p = 0;
#pragma unroll 2
    for (int step = 0; step < T_; ++step) {
        // depth-2 prefetch (consumed at step+2; wraps harmlessly at tail)
        f32x4 p2A = *(const f32x4*)(projC + xT[(step + 2) & (T_ - 1)][q] * G4_ + u * 4);

        // A-fragments of h_t (conflict-free lane-contiguous b128)
        const f16x8 a0 = *(const f16x8*)(hf[p] + l * 8);
        const f16x8 a1 = *(const f16x8*)(hf[p] + 512 + l * 8);

        // gates for (row q, unit u): only C-reg[0] is live
        f32x4 z4 = {0.0f, 0.0f, 0.0f, 0.0f};
        float gA[4];
#pragma unroll
        for (int jj = 0; jj < 4; ++jj) {
            f32x4 d0 = __builtin_amdgcn_mfma_f32_16x16x32_f16(a0, bf[jj][0], z4, 0, 0, 0);
            f32x4 d1 = __builtin_amdgcn_mfma_f32_16x16x32_f16(a1, bf[jj][1], z4, 0, 0, 0);
            gA[jj] = d0[0] + d1[0];
        }

        // cell update; pp was loaded 2 steps ago (never waited)
        float iA = sigm(gA[0] + ppA.x);
        float fA = sigm(gA[1] + ppA.y);
        float ggA = tanhr(gA[2] + ppA.z);
        float oA = sigm(gA[3] + ppA.w);
        cA = fA * cA + iA * ggA;
        hA = oA * tanhr(cA);

        // publish h_{t+1} (A-layout, other buffer)
        hf[p ^ 1][hbase] = (half1)hA;

        ppA = pnA;
        pnA = p2A;
        p ^= 1;
        lds_barrier();  // lgkmcnt-only: proj prefetches stay in flight
    }

    // epilogue: logits + fused loss
    hfin[q][u] = hA;
    __syncthreads();
    int m4 = t >> 6, uu = t & 63;  // wave m4 reduces batch row m4
    float part = hfin[m4][uu] * Wfc[uu];
#pragma unroll
    for (int off = 32; off > 0; off >>= 1) part += __shfl_down(part, off, 64);
    if (uu == 0) {
        float z = part + bfc[0];
        logits[b0 + m4] = z;
        float tg = targets[b0 + m4];
        float e = EXP2F(-1.44269504f * fabsf(z));
        float lsp = fminf(z, 0.0f) - log1pf(e);
        float lsn = lsp - z;
        zred[m4] = -(POS_W * tg * lsp + (1.0f - tg) * lsn) * (1.0f / (float)B_);
    }
    __syncthreads();
    if (t == 0) {
        float s = 0.0f;
#pragma unroll
        for (int i = 0; i < MB_; ++i) s += zred[i];
        atomicAdd(loss_slot, s);
    }
}

// ---------------------------------------------------------------------------
extern "C" void kernel_launch(void* const* d_in, const int* in_sizes, int n_in,
                              void* d_out, int out_size, void* d_ws, size_t ws_size,
                              hipStream_t stream) {
    const int* x = (const int*)d_in[0];
    const float* targets = (const float*)d_in[1];
    const float* emb = (const float*)d_in[2];
    const float* Wih = (const float*)d_in[3];
    const float* Whh = (const float*)d_in[4];
    const float* bih = (const float*)d_in[5];
    const float* bhh = (const float*)d_in[6];
    const float* Wfc = (const float*)d_in[7];
    const float* bfc = (const float*)d_in[8];
    float* out = (float*)d_out;  // [0..2047] logits, [2048] loss

    float* projC = (float*)d_ws;  // 128*256*4 = 128 KiB

    k_prep<<<dim3(V_), dim3(256), 0, stream>>>(emb, Wih, bih, bhh, projC, out + B_);
    k_lstm<<<dim3(NBLK_), dim3(256), 0, stream>>>(x, Whh, projC, Wfc, bfc, targets, out,
                                                  out + B_);
}

// Round 9
// 162.194 us; speedup vs baseline: 1.8356x; 1.0079x over previous
//
#include <hip/hip_runtime.h>
#include <stdint.h>

#define B_ 2048
#define T_ 256
#define V_ 128
#define E_ 128
#define H_ 64
#define G4_ 256  // 4*H
#define POS_W 20.0f
#define MB_ 4            // batch rows per block: row j at M-row 4j (C-reg[0] of lane quad j)
#define NBLK_ (B_ / MB_) // 512 blocks = 2 blocks/CU = 2 waves/SIMD
typedef _Float16 half1;
typedef __attribute__((ext_vector_type(8))) _Float16 f16x8;
typedef __attribute__((ext_vector_type(4))) float f32x4;

#if __has_builtin(__builtin_amdgcn_exp2f)
#define EXP2F(x) __builtin_amdgcn_exp2f(x)
#else
#define EXP2F(x) exp2f(x)
#endif

#if __has_builtin(__builtin_amdgcn_rcpf)
#define RCPF(x) __builtin_amdgcn_rcpf(x)
#else
#define RCPF(x) (1.0f / (x))
#endif

__device__ __forceinline__ float sigm(float x) {
    return RCPF(1.0f + EXP2F(-1.44269504f * x));
}
__device__ __forceinline__ float tanhr(float x) {
    // tanh(x) = 1 - 2/(e^(2x)+1); exp2 over/underflow saturates correctly
    float t = EXP2F(2.88539008f * x);
    return 1.0f - 2.0f * RCPF(t + 1.0f);
}

// Barrier draining ONLY lgkmcnt: keeps L2 proj-prefetches (vmcnt) in flight
// across the step boundary (R6->R7: 1422 -> 1000 cyc/step). Safe: h-exchange
// is double-buffered; in-flight global loads only write registers.
__device__ __forceinline__ void lds_barrier() {
    asm volatile("s_waitcnt lgkmcnt(0)\n\ts_barrier" ::: "memory");
}

// ---------------------------------------------------------------------------
// k_prep: projC[v][u][g] = dot(emb[v], W_ih[g*64+u]) + b_ih + b_hh   (f32)
// Layout [v][unit][gate]: LSTM kernel gathers one float4 per (v,unit).
// Block 0 / tid 0 zeroes the loss accumulator.
// ---------------------------------------------------------------------------
__global__ void k_prep(const float* __restrict__ emb, const float* __restrict__ Wih,
                       const float* __restrict__ bih, const float* __restrict__ bhh,
                       float* __restrict__ projC, float* __restrict__ loss_slot) {
    int tid = threadIdx.x;  // 0..255; u = tid>>2, g = tid&3
    int v = blockIdx.x;
    if (v == 0 && tid == 0) *loss_slot = 0.0f;
    int u = tid >> 2, g = tid & 3;
    int row = g * 64 + u;
    const float4* e4 = (const float4*)(emb + v * E_);
    const float4* w4 = (const float4*)(Wih + row * E_);
    float acc = bih[row] + bhh[row];
#pragma unroll
    for (int i = 0; i < E_ / 4; ++i) {
        float4 a = e4[i];
        float4 b = w4[i];
        acc += a.x * b.x + a.y * b.y + a.z * b.z + a.w * b.w;
    }
    projC[v * G4_ + tid] = acc;  // coalesced
}

// ---------------------------------------------------------------------------
// k_lstm: MFMA recurrence, gate-permuted B, 1 cell per thread.
// Block = 4 batch rows (4 waves); 512 blocks -> 2 blocks/CU.
// R8 analysis: the two co-resident blocks phase-lock at their barriers
// (identical per-step work) and serialize: step = 2 x 472 issue-cyc = 944.
// Fix: odd blocks s_sleep ~448 cyc once before the loop, de-phasing the
// pair so each block's VALU burst fills the other's barrier wait.
// ---------------------------------------------------------------------------
__launch_bounds__(256, 2)
__global__ void k_lstm(const int* __restrict__ x, const float* __restrict__ Whh,
                       const float* __restrict__ projC, const float* __restrict__ Wfc,
                       const float* __restrict__ bfc, const float* __restrict__ targets,
                       float* __restrict__ logits, float* __restrict__ loss_slot) {
    int b0 = blockIdx.x * MB_;
    int t = threadIdx.x;         // 0..255
    int w = t >> 6, l = t & 63;  // wave, lane
    int q = l >> 4, cc = l & 15;
    int u = 16 * w + cc;  // unit owned by this lane (all 4 gates), batch row q

    __shared__ __align__(16) half1 hf[2][1024];  // A-layout h, double-buffered
    __shared__ int xT[T_][MB_];                  // transposed token indices
    __shared__ float hfin[MB_][68];              // final h (padded)
    __shared__ float zred[MB_];

    // stage xT (coalesced: fixed i, consecutive t)
#pragma unroll
    for (int i = 0; i < MB_; ++i) xT[t][i] = x[(b0 + i) * T_ + t];
    ((float*)hf)[t] = 0.0f;
    ((float*)hf)[t + 256] = 0.0f;
    ((float*)hf)[t + 512] = 0.0f;
    ((float*)hf)[t + 768] = 0.0f;
    __syncthreads();

    // B-fragments inline from W_hh (f32, L2): N-tile jj, K-chunk c.
    // frag elem j: B[k=c*32+q*8+j][col cc] = Whh[jj*64+16w+cc][k]  (R5-R8 verified)
    f16x8 bf[4][2];
#pragma unroll
    for (int jj = 0; jj < 4; ++jj) {
#pragma unroll
        for (int c = 0; c < 2; ++c) {
            int row = jj * 64 + 16 * w + cc;
            int kb = c * 32 + q * 8;
            float4 w0 = *(const float4*)(Whh + row * H_ + kb);
            float4 w1 = *(const float4*)(Whh + row * H_ + kb + 4);
            f16x8 tmp;
            tmp[0] = (half1)w0.x; tmp[1] = (half1)w0.y;
            tmp[2] = (half1)w0.z; tmp[3] = (half1)w0.w;
            tmp[4] = (half1)w1.x; tmp[5] = (half1)w1.y;
            tmp[6] = (half1)w1.z; tmp[7] = (half1)w1.w;
            bf[jj][c] = tmp;
        }
    }

    // h-write slot for (unit u, M-row 4q):
    // f16 idx = (u>>5)*512 + ((u>>3)&3)*128 + (4q)*8 + (u&7)
    int hbase = (u >> 5) * 512 + ((u >> 3) & 3) * 128 + (4 * q) * 8 + (u & 7);

    float cA = 0.0f, hA = 0.0f;

    // prefetch proj for steps 0 and 1 (depth 2); same-q lanes broadcast-read xT
    f32x4 ppA = *(const f32x4*)(projC + xT[0][q] * G4_ + u * 4);
    f32x4 pnA = *(const f32x4*)(projC + xT[1][q] * G4_ + u * 4);

    // De-phase the two co-resident blocks: odd blocks sleep ~448 cyc (~half a
    // step) so the pair interleaves instead of convoying at the barrier.
    if (blockIdx.x & 1) {
        asm volatile("s_sleep 7");
    }

    int p = 0;
#pragma unroll 2
    for (int step = 0; step < T_; ++step) {
        // depth-2 prefetch (consumed at step+2; wraps harmlessly at tail)
        f32x4 p2A = *(const f32x4*)(projC + xT[(step + 2) & (T_ - 1)][q] * G4_ + u * 4);

        // A-fragments of h_t (conflict-free lane-contiguous b128)
        const f16x8 a0 = *(const f16x8*)(hf[p] + l * 8);
        const f16x8 a1 = *(const f16x8*)(hf[p] + 512 + l * 8);

        // gates for (row q, unit u): only C-reg[0] is live
        f32x4 z4 = {0.0f, 0.0f, 0.0f, 0.0f};
        float gA[4];
#pragma unroll
        for (int jj = 0; jj < 4; ++jj) {
            f32x4 d0 = __builtin_amdgcn_mfma_f32_16x16x32_f16(a0, bf[jj][0], z4, 0, 0, 0);
            f32x4 d1 = __builtin_amdgcn_mfma_f32_16x16x32_f16(a1, bf[jj][1], z4, 0, 0, 0);
            gA[jj] = d0[0] + d1[0];
        }

        // cell update; pp was loaded 2 steps ago (never waited)
        float iA = sigm(gA[0] + ppA.x);
        float fA = sigm(gA[1] + ppA.y);
        float ggA = tanhr(gA[2] + ppA.z);
        float oA = sigm(gA[3] + ppA.w);
        cA = fA * cA + iA * ggA;
        hA = oA * tanhr(cA);

        // publish h_{t+1} (A-layout, other buffer)
        hf[p ^ 1][hbase] = (half1)hA;

        ppA = pnA;
        pnA = p2A;
        p ^= 1;
        lds_barrier();  // lgkmcnt-only: proj prefetches stay in flight
    }

    // epilogue: logits + fused loss
    hfin[q][u] = hA;
    __syncthreads();
    int m4 = t >> 6, uu = t & 63;  // wave m4 reduces batch row m4
    float part = hfin[m4][uu] * Wfc[uu];
#pragma unroll
    for (int off = 32; off > 0; off >>= 1) part += __shfl_down(part, off, 64);
    if (uu == 0) {
        float z = part + bfc[0];
        logits[b0 + m4] = z;
        float tg = targets[b0 + m4];
        float e = EXP2F(-1.44269504f * fabsf(z));
        float lsp = fminf(z, 0.0f) - log1pf(e);
        float lsn = lsp - z;
        zred[m4] = -(POS_W * tg * lsp + (1.0f - tg) * lsn) * (1.0f / (float)B_);
    }
    __syncthreads();
    if (t == 0) {
        float s = 0.0f;
#pragma unroll
        for (int i = 0; i < MB_; ++i) s += zred[i];
        atomicAdd(loss_slot, s);
    }
}

// ---------------------------------------------------------------------------
extern "C" void kernel_launch(void* const* d_in, const int* in_sizes, int n_in,
                              void* d_out, int out_size, void* d_ws, size_t ws_size,
                              hipStream_t stream) {
    const int* x = (const int*)d_in[0];
    const float* targets = (const float*)d_in[1];
    const float* emb = (const float*)d_in[2];
    const float* Wih = (const float*)d_in[3];
    const float* Whh = (const float*)d_in[4];
    const float* bih = (const float*)d_in[5];
    const float* bhh = (const float*)d_in[6];
    const float* Wfc = (const float*)d_in[7];
    const float* bfc = (const float*)d_in[8];
    float* out = (float*)d_out;  // [0..2047] logits, [2048] loss

    float* projC = (float*)d_ws;  // 128*256*4 = 128 KiB

    k_prep<<<dim3(V_), dim3(256), 0, stream>>>(emb, Wih, bih, bhh, projC, out + B_);
    k_lstm<<<dim3(NBLK_), dim3(256), 0, stream>>>(x, Whh, projC, Wfc, bfc, targets, out,
                                                  out + B_);
}